// Round 9
// baseline (286.082 us; speedup 1.0000x reference)
//
#include <hip/hip_runtime.h>
#include <hip/hip_bf16.h>

#define HID 256
#define QD 64
#define NSEG 16
#define SLQ 2048
#define SLH 2048

// Fragment-packed layouts (all produced in-kernel, consumed lane-linearly):
//  kb (per seg): unit (g*2+p) of 512 shorts; element (key g*16+l16,
//     col p*32+quad*8+j) at kb + seg*131072 + (g*2+p)*512 + lane*8 + j.
//  vt (per seg): unit ((kt*4+ks)*16+d16); element (dim d16*16+l16,
//     key kt*128+ks*32+quad*8+j) at vt + seg*524288 + unit*512 + lane*8 + j.
//  weights (WQ/WK/WV/fc_w): unit (n*8+ks); element (row n*16+l16,
//     col ks*32+quad*8+j) at w + ((n*8+ks)*64+lane)*8 + j.
// History: r4 lane-linear K/V frags = attn 2x (VMEM transaction bound).
// r5/r6 producer nulls + ledger: total ≈ Σkernels + ~140us in EVERY round —
// suspected inter-dispatch overhead. r8: cooperative launch never ran (graph
// capture incompatibility; output stayed zero). r9 (this): same single-kernel
// experiment with a MANUAL grid barrier (device-scope atomics in d_ws, zeroed
// via hipMemsetAsync each launch) + normal <<<512,512>>> launch. Grid is
// co-resident by construction (launch_bounds(512,4) -> 2 blocks/CU x 256 CU).

typedef __attribute__((ext_vector_type(8))) short bf16x8;
typedef __attribute__((ext_vector_type(8))) __bf16 bf16x8b;
typedef __attribute__((ext_vector_type(4))) float f32x4;
typedef __attribute__((ext_vector_type(4))) short s16x4;

// LDS-only barrier: completes this wave's LDS ops (lgkmcnt) and syncs, but does
// NOT drain outstanding global loads (vmcnt) the way __syncthreads() does.
#define BAR_LDS() asm volatile("s_waitcnt lgkmcnt(0)\n\ts_barrier" ::: "memory")

static __device__ __forceinline__ f32x4 mfma16(bf16x8 a, bf16x8 b, f32x4 c) {
  return __builtin_amdgcn_mfma_f32_16x16x32_bf16(
      __builtin_bit_cast(bf16x8b, a), __builtin_bit_cast(bf16x8b, b), c, 0, 0, 0);
}

static __device__ __forceinline__ short f2bf(float x) {
  union { float f; unsigned u; } v; v.f = x;
  unsigned r = v.u + 0x7fffu + ((v.u >> 16) & 1u);
  return (short)(r >> 16);
}

static __device__ __forceinline__ float bf2f(short s) {
  union { unsigned u; float f; } v;
  v.u = ((unsigned)(unsigned short)s) << 16;
  return v.f;
}

// Pack one weight element into fragment-linear order. i = packed short index.
static __device__ __forceinline__ void pack_w(const float* __restrict__ s,
                                              short* __restrict__ d, int i) {
  int j = i & 7, l16 = (i >> 3) & 15, quad = (i >> 7) & 3, ks = (i >> 9) & 7,
      n = i >> 12;
  d[i] = f2bf(s[(size_t)(n * 16 + l16) * HID + ks * 32 + quad * 8 + j]);
}

// Manual grid barrier (counters zeroed by hipMemsetAsync each launch).
// __syncthreads() at entry drains each wave's vmcnt -> all block stores
// complete; thread 0's release fence publishes (cross-XCD L2 writeback),
// device-scope atomics carry the rendezvous, acquire fence invalidates
// local L2 so post-barrier plain loads see remote writes.
static __device__ __forceinline__ void grid_barrier(unsigned* cnt,
                                                    unsigned* flag,
                                                    unsigned nblk) {
  __syncthreads();
  if (threadIdx.x == 0) {
    __threadfence();
    unsigned old = atomicAdd(cnt, 1u);
    if (old == nblk - 1u) {
      atomicExch(flag, 1u);
    } else {
      while (atomicAdd(flag, 0u) == 0u) __builtin_amdgcn_s_sleep(2);
    }
    __threadfence();
  }
  __syncthreads();
}

// Single kernel: A0 cast+pack | gbar | A1 kv-proj | gbar | B fused attn.
// 512 blocks x 512 threads, __launch_bounds__(512,4): VGPR<=128 and LDS
// 44.5KB guarantee 2 blocks/CU -> entire grid co-resident (spin-safe).
__global__ __launch_bounds__(512, 4) void fused_kernel(
    const float* __restrict__ q, const float* __restrict__ h,
    const float* __restrict__ WQ, const float* __restrict__ WK,
    const float* __restrict__ WV, const float* __restrict__ fcw,
    const float* __restrict__ fcb, const float* __restrict__ n0w,
    const float* __restrict__ n0b, const float* __restrict__ n1w,
    const float* __restrict__ n1b, short* __restrict__ wqb,
    short* __restrict__ wkb, short* __restrict__ wvb,
    short* __restrict__ fwb, short* __restrict__ kb,
    short* __restrict__ vt, unsigned* __restrict__ bar,
    float* __restrict__ out) {
  __shared__ short p_lds[2][64][136];  // 34.8KB; A1 hb/vbuf alias; B staging/P/ob
  __shared__ short qx[4096];           // 8KB packed q-fragment bounce
  __shared__ float plsum[4][2][16];    // [qg][kh][row16] partial softmax sums
  __shared__ float rs[2][2][64];       // [s|s2][kh][row] LN1 partial sums

  int wave = threadIdx.x >> 6, lane = threadIdx.x & 63;
  int quad = lane >> 4, l16 = lane & 15;
  int b = blockIdx.x;

  // ---------------- A0: weight cast+pack (1 elem/thread) ----------------
  {
    int gi = b * 512 + threadIdx.x;
    if (gi < 16384) pack_w(WQ, wqb, gi);
    else if (gi < 32768) pack_w(WK, wkb, gi - 16384);
    else if (gi < 98304) pack_w(WV, wvb, gi - 32768);
    else if (gi < 163840) pack_w(fcw, fwb, gi - 98304);
  }
  grid_barrier(bar + 0, bar + 16, 512u);

  // ---------------- A1: k/v projection of this block's 64-row h tile -------
  // 8 waves: wave&3 picks the 16-token slice; wave>>2 picks the V-dim half.
  // Waves 0-3 additionally compute the K projection.
  {
    short (*hb)[264] = (short(*)[264]) & p_lds[0][0][0];
    int m0 = b * 64;
#pragma unroll
    for (int i = 0; i < 8; ++i) {
      int idx = i * 512 + threadIdx.x;
      int row = idx >> 6, col = (idx & 63) * 4;
      f32x4 v = *(const f32x4*)(h + (size_t)(m0 + row) * HID + col);
      s16x4 pk;
#pragma unroll
      for (int j = 0; j < 4; ++j) pk[j] = f2bf(v[j]);
      *(s16x4*)&hb[row][col] = pk;
    }
    __syncthreads();
    int mw = (wave & 3) * 16;
    int mtb = (wave >> 2) * 8;
    f32x4 kacc[4];
    f32x4 vacc[8];
#pragma unroll
    for (int n = 0; n < 4; ++n) kacc[n] = f32x4{0.f, 0.f, 0.f, 0.f};
#pragma unroll
    for (int n = 0; n < 8; ++n) vacc[n] = f32x4{0.f, 0.f, 0.f, 0.f};
#pragma unroll
    for (int ks = 0; ks < 8; ++ks) {
      bf16x8 a = *(const bf16x8*)&hb[mw + l16][ks * 32 + quad * 8];
      if (wave < 4) {
#pragma unroll
        for (int n = 0; n < 4; ++n) {
          bf16x8 wb = *(const bf16x8*)(wkb + (size_t)((n * 8 + ks) * 64 + lane) * 8);
          kacc[n] = mfma16(a, wb, kacc[n]);
        }
      }
#pragma unroll
      for (int mt = 0; mt < 8; ++mt) {
        bf16x8 wf = *(const bf16x8*)(wvb + (size_t)(((mtb + mt) * 8 + ks) * 64 + lane) * 8);
        vacc[mt] = mfma16(wf, a, vacc[mt]);  // D[m=dv][n=tok] = WV @ h^T
      }
    }
    __syncthreads();  // ALL waves' hb reads done before bounce writes rows
    if (wave < 4) {
      // packed kb write; bounce in this wave's own (now dead) hb rows
      char* kx = (char*)&hb[mw][0];
#pragma unroll
      for (int n = 0; n < 4; ++n)
#pragma unroll
        for (int r = 0; r < 4; ++r) {
          int k16 = quad * 4 + r;
          int bo = (k16 * 128 + (n * 16 + l16) * 2) ^ ((k16 & 7) << 4);
          *(short*)(kx + bo) = f2bf(kacc[n][r]);
        }
      asm volatile("s_waitcnt lgkmcnt(0)" ::: "memory");
      int seg = (m0 + mw) >> 11;
      int g = ((m0 + mw) & 2047) >> 4;
      short* kdst = kb + (size_t)seg * 131072 + (size_t)g * 1024 + lane * 8;
#pragma unroll
      for (int p = 0; p < 2; ++p) {
        int bo = (l16 * 128 + p * 64 + quad * 16) ^ ((l16 & 7) << 4);
        *(bf16x8*)(kdst + p * 512) = *(bf16x8*)(kx + bo);
      }
    }
    __syncthreads();  // bounce reads drained -> safe to reuse hb as vbuf
    {
      char* vbuf = (char*)&hb[0][0];  // 32KB
#pragma unroll
      for (int mt = 0; mt < 8; ++mt)
#pragma unroll
        for (int r = 0; r < 4; ++r) {
          int dv = (mtb + mt) * 16 + quad * 4 + r;
          int bo = (dv * 128 + (mw + l16) * 2) ^ ((dv & 7) << 4);
          *(short*)(vbuf + bo) = f2bf(vacc[mt][r]);
        }
      __syncthreads();
      // packed vt write-out: 32 units of 1KB; 4 per wave, fully coalesced
      int seg = m0 >> 11;
      int t0 = m0 & 2047;
      int kt = t0 >> 7;
      int ksb = (t0 >> 5) & 3;  // 0 or 2 (tiles are 64-token aligned)
      short* vdst = vt + (size_t)seg * 524288;
#pragma unroll
      for (int i = 0; i < 4; ++i) {
        int u = wave * 4 + i;
        int ksl = u >> 4, d16 = u & 15;
        int dim = d16 * 16 + l16;
        int bo = (dim * 128 + ksl * 64 + quad * 16) ^ ((dim & 7) << 4);
        size_t unit = (size_t)((kt * 4 + ksb + ksl) * 16 + d16);
        *(bf16x8*)(vdst + unit * 512 + lane * 8) = *(bf16x8*)(vbuf + bo);
      }
    }
  }
  grid_barrier(bar + 32, bar + 48, 512u);

  // ---------------- B: fused attention (r7 code, unchanged) ----------------
  int qg = wave >> 1, kh = wave & 1;
  int xcd = b & 7, li = b >> 3;
  int seg = xcd * 2 + (li >> 5);
  int tile = li & 31;
  int qrow0 = seg * SLQ + tile * 64;
  const short* kseg = kb + (size_t)seg * 131072;
  const short* vseg = vt + (size_t)seg * 524288;

  const float cexp = 0.125f * 1.44269504f;  // scale * log2(e)
  bf16x8 kpre[4][2];

#define LOADK(KT)                                                               \
  {                                                                             \
    _Pragma("unroll") for (int t = 0; t < 4; ++t) {                             \
      const short* kp = kseg + (size_t)((KT) * 8 + kh * 4 + t) * 1024 + lane * 8;\
      kpre[t][0] = *(const bf16x8*)kp;                                          \
      kpre[t][1] = *(const bf16x8*)(kp + 512);                                  \
    }                                                                           \
  }

  // first K-tile loads fly during the q-proj prologue (kb valid after gbar)
  LOADK(tile & 15)

  // ---- prologue: q projection ----
  short (*st)[264] = (short(*)[264]) & p_lds[0][0][0];
  bf16x8 qf0, qf1;
  {
    const float* qsrc = q + (size_t)qrow0 * HID;
#pragma unroll
    for (int i = 0; i < 8; ++i) {
      int idx = i * 512 + threadIdx.x;
      int row = idx >> 6, col = (idx & 63) * 4;
      f32x4 v = *(const f32x4*)(qsrc + (size_t)row * HID + col);
      s16x4 pk;
#pragma unroll
      for (int j = 0; j < 4; ++j) pk[j] = f2bf(v[j]);
      *(s16x4*)&st[row][col] = pk;
    }
    __syncthreads();
    f32x4 qacc[2];
    qacc[0] = f32x4{0.f, 0.f, 0.f, 0.f};
    qacc[1] = f32x4{0.f, 0.f, 0.f, 0.f};
#pragma unroll
    for (int ks = 0; ks < 8; ++ks) {
      bf16x8 a = *(const bf16x8*)&st[qg * 16 + l16][ks * 32 + quad * 8];
#pragma unroll
      for (int ni = 0; ni < 2; ++ni) {
        int n = kh * 2 + ni;
        bf16x8 wb = *(const bf16x8*)(wqb + (size_t)((n * 8 + ks) * 64 + lane) * 8);
        qacc[ni] = mfma16(a, wb, qacc[ni]);
      }
    }
    BAR_LDS();  // all st reads done block-wide before S_PHASE may overwrite
#pragma unroll
    for (int ni = 0; ni < 2; ++ni)
#pragma unroll
      for (int r = 0; r < 4; ++r) {
        int n = kh * 2 + ni;
        int colp = (n & 1) * 16 + l16;
        qx[(qg * 2 + (n >> 1)) * 512 + ((colp >> 3) * 16 + quad * 4 + r) * 8 +
           (colp & 7)] = f2bf(qacc[ni][r]);
      }
    BAR_LDS();
    const short* qxp = qx + qg * 1024 + lane * 8;
    qf0 = *(const bf16x8*)qxp;
    qf1 = *(const bf16x8*)(qxp + 512);
  }

  f32x4 o[4][2];  // [qrow-group m][dim-group n]: 64 rows x 32 dims per wave
#pragma unroll
  for (int m = 0; m < 4; ++m)
#pragma unroll
    for (int n = 0; n < 2; ++n) o[m][n] = f32x4{0.f, 0.f, 0.f, 0.f};
  float lsum = 0.f;

#define S_PHASE(BUF)                                                            \
  {                                                                             \
    f32x4 s[4];                                                                 \
    _Pragma("unroll") for (int t = 0; t < 4; ++t) {                             \
      f32x4 a = f32x4{0.f, 0.f, 0.f, 0.f};                                      \
      a = mfma16(kpre[t][0], qf0, a);                                           \
      a = mfma16(kpre[t][1], qf1, a);                                           \
      s[t] = a;                                                                 \
    }                                                                           \
    _Pragma("unroll") for (int t = 0; t < 4; ++t) {                             \
      float p0 = __builtin_amdgcn_exp2f(s[t][0] * cexp);                        \
      float p1 = __builtin_amdgcn_exp2f(s[t][1] * cexp);                        \
      float p2 = __builtin_amdgcn_exp2f(s[t][2] * cexp);                        \
      float p3 = __builtin_amdgcn_exp2f(s[t][3] * cexp);                        \
      lsum += (p0 + p1) + (p2 + p3);                                            \
      s16x4 pk;                                                                 \
      pk[0] = f2bf(p0); pk[1] = f2bf(p1); pk[2] = f2bf(p2); pk[3] = f2bf(p3);   \
      *(s16x4*)&p_lds[BUF][qg * 16 + l16][kh * 64 + t * 16 + quad * 4] = pk;    \
    }                                                                           \
  }

#define PV_PHASE(KT, BUF)                                                       \
  {                                                                             \
    _Pragma("unroll") for (int ks = 0; ks < 4; ++ks) {                          \
      bf16x8 pf[4];                                                             \
      _Pragma("unroll") for (int m = 0; m < 4; ++m)                             \
        pf[m] = *(const bf16x8*)&p_lds[BUF][m * 16 + l16][ks * 32 + quad * 8];  \
      _Pragma("unroll") for (int n = 0; n < 2; ++n) {                           \
        const short* vp = vseg +                                                \
            ((size_t)((KT) * 4 + ks) * 16 + wave * 2 + n) * 512 + lane * 8;     \
        bf16x8 vf = *(const bf16x8*)vp;                                         \
        _Pragma("unroll") for (int m = 0; m < 4; ++m)                           \
          o[m][n] = mfma16(pf[m], vf, o[m][n]);                                 \
      }                                                                         \
    }                                                                           \
  }

  // staggered key-tile order (r2, kept): block at q-tile `tile` starts at tile&15
  S_PHASE(0)
  LOADK((tile + 1) & 15)
  BAR_LDS();
#pragma unroll 1
  for (int j = 1; j < 16; ++j) {
    S_PHASE(j & 1)
    if (j < 15) LOADK((tile + j + 1) & 15)
    PV_PHASE((tile + j - 1) & 15, (j - 1) & 1)
    BAR_LDS();
  }
  PV_PHASE((tile + 15) & 15, 1)

  // per-wave lsum: reduce over quads -> lane l16 holds this wave's partial
  lsum += __shfl_xor(lsum, 16);
  lsum += __shfl_xor(lsum, 32);

  BAR_LDS();  // all PV LDS reads done before o-staging overwrites p_lds
  if (lane < 16) plsum[qg][kh][lane] = lsum;
  short (*ob)[264] = (short(*)[264]) & p_lds[0][0][0];
#pragma unroll
  for (int m = 0; m < 4; ++m)
#pragma unroll
    for (int n = 0; n < 2; ++n)
#pragma unroll
      for (int r = 0; r < 4; ++r)
        ob[m * 16 + quad * 4 + r][wave * 32 + n * 16 + l16] = f2bf(o[m][n][r]);
  BAR_LDS();

  // ---- LN0 (x written in-place into ob) ----
  {
    int row = wave * 8 + (lane >> 3);
    int c0 = (lane & 7) * 32;
    float linv = 1.f / (plsum[row >> 4][0][row & 15] + plsum[row >> 4][1][row & 15]);
    float y[32];
    float s1 = 0.f, s2 = 0.f;
    const float* qp = q + (size_t)(qrow0 + row) * HID + c0;
#pragma unroll
    for (int k = 0; k < 4; ++k) {
      bf16x8 ov = *(const bf16x8*)&ob[row][c0 + k * 8];
      f32x4 qa = *(const f32x4*)(qp + k * 8);
      f32x4 qb = *(const f32x4*)(qp + k * 8 + 4);
#pragma unroll
      for (int j = 0; j < 4; ++j) {
        float yv = qa[j] + bf2f(ov[j]) * linv;
        y[k * 8 + j] = yv;
        s1 += yv; s2 += yv * yv;
      }
#pragma unroll
      for (int j = 0; j < 4; ++j) {
        float yv = qb[j] + bf2f(ov[4 + j]) * linv;
        y[k * 8 + 4 + j] = yv;
        s1 += yv; s2 += yv * yv;
      }
    }
    s1 += __shfl_xor(s1, 1); s2 += __shfl_xor(s2, 1);
    s1 += __shfl_xor(s1, 2); s2 += __shfl_xor(s2, 2);
    s1 += __shfl_xor(s1, 4); s2 += __shfl_xor(s2, 4);
    float mean = s1 * (1.f / HID);
    float var = s2 * (1.f / HID) - mean * mean;
    float rstd = rsqrtf(var + 1e-5f);
#pragma unroll
    for (int k = 0; k < 4; ++k) {
      f32x4 wa = *(const f32x4*)(n0w + c0 + k * 8);
      f32x4 wb = *(const f32x4*)(n0w + c0 + k * 8 + 4);
      f32x4 ba = *(const f32x4*)(n0b + c0 + k * 8);
      f32x4 bb = *(const f32x4*)(n0b + c0 + k * 8 + 4);
      s16x4 o0, o1;
#pragma unroll
      for (int j = 0; j < 4; ++j) {
        o0[j] = f2bf((y[k * 8 + j] - mean) * rstd * wa[j] + ba[j]);
        o1[j] = f2bf((y[k * 8 + 4 + j] - mean) * rstd * wb[j] + bb[j]);
      }
      // in-place: this thread exclusively owns (row, c0..c0+31)
      *(s16x4*)&ob[row][c0 + k * 8] = o0;
      *(s16x4*)&ob[row][c0 + k * 8 + 4] = o1;
    }
  }
  BAR_LDS();  // x tile complete and visible

  // ---- FC GEMM + LN1 ----
  {
    f32x4 facc[8];
#pragma unroll
    for (int n2 = 0; n2 < 8; ++n2) facc[n2] = f32x4{0.f, 0.f, 0.f, 0.f};
#pragma unroll
    for (int ks = 0; ks < 8; ++ks) {
      bf16x8 a = *(const bf16x8*)&ob[qg * 16 + l16][ks * 32 + quad * 8];
#pragma unroll
      for (int n2 = 0; n2 < 8; ++n2) {
        int n = kh * 8 + n2;
        bf16x8 wb = *(const bf16x8*)(fwb + (size_t)((n * 8 + ks) * 64 + lane) * 8);
        facc[n2] = mfma16(a, wb, facc[n2]);
      }
    }
#pragma unroll
    for (int r = 0; r < 4; ++r) {
      int row = qg * 16 + quad * 4 + r;
      float s = 0.f, s2 = 0.f;
#pragma unroll
      for (int n2 = 0; n2 < 8; ++n2) {
        int col = kh * 128 + n2 * 16 + l16;
        float hres = fmaxf(facc[n2][r] + fcb[col], 0.f);
        float yv = bf2f(ob[row][col]) + hres;
        s += yv; s2 += yv * yv;
      }
      s += __shfl_xor(s, 1); s2 += __shfl_xor(s2, 1);
      s += __shfl_xor(s, 2); s2 += __shfl_xor(s2, 2);
      s += __shfl_xor(s, 4); s2 += __shfl_xor(s2, 4);
      s += __shfl_xor(s, 8); s2 += __shfl_xor(s2, 8);
      if (l16 == 0) { rs[0][kh][row] = s; rs[1][kh][row] = s2; }
    }
    BAR_LDS();
#pragma unroll
    for (int r = 0; r < 4; ++r) {
      int row = qg * 16 + quad * 4 + r;
      float st1 = rs[0][0][row] + rs[0][1][row];
      float st2 = rs[1][0][row] + rs[1][1][row];
      float mean = st1 * (1.f / HID);
      float var = st2 * (1.f / HID) - mean * mean;
      float rstd = rsqrtf(var + 1e-5f);
      float* op = out + (size_t)(qrow0 + row) * HID;
#pragma unroll
      for (int n2 = 0; n2 < 8; ++n2) {
        int col = kh * 128 + n2 * 16 + l16;
        float hres = fmaxf(facc[n2][r] + fcb[col], 0.f);
        float yv = bf2f(ob[row][col]) + hres;
        op[col] = (yv - mean) * rstd * n1w[col] + n1b[col];
      }
    }
  }
#undef LOADK
#undef S_PHASE
#undef PV_PHASE
}

extern "C" void kernel_launch(void* const* d_in, const int* in_sizes, int n_in,
                              void* d_out, int out_size, void* d_ws, size_t ws_size,
                              hipStream_t stream) {
  const float* q = (const float*)d_in[0];
  const float* h = (const float*)d_in[1];
  const float* WQ = (const float*)d_in[2];
  const float* WK = (const float*)d_in[3];
  const float* WV = (const float*)d_in[4];
  const float* fc_w = (const float*)d_in[5];
  const float* fc_b = (const float*)d_in[6];
  const float* n0w = (const float*)d_in[7];
  const float* n0b = (const float*)d_in[8];
  const float* n1w = (const float*)d_in[9];
  const float* n1b = (const float*)d_in[10];

  char* ws = (char*)d_ws;
  short* kb = (short*)(ws);                            //  4 MB  [0,4)  packed
  short* vt = (short*)(ws + ((size_t)4 << 20));        // 16 MB  [4,20) packed
  short* wqb = (short*)(ws + ((size_t)20 << 20));
  short* wkb = (short*)(ws + ((size_t)20 << 20) + 32 * 1024);
  short* wvb = (short*)(ws + ((size_t)20 << 20) + 64 * 1024);
  short* fwb = (short*)(ws + ((size_t)20 << 20) + 192 * 1024);
  unsigned* bar = (unsigned*)(ws + ((size_t)21 << 20));  // 256B barrier state

  hipMemsetAsync(bar, 0, 256, stream);
  fused_kernel<<<512, 512, 0, stream>>>(q, h, WQ, WK, WV, fc_w, fc_b,
                                        n0w, n0b, n1w, n1b, wqb, wkb, wvb,
                                        fwb, kb, vt, bar, (float*)d_out);
}

// Round 10
// 252.834 us; speedup vs baseline: 1.1315x; 1.1315x over previous
//
#include <hip/hip_runtime.h>
#include <hip/hip_bf16.h>

#define HID 256
#define QD 64
#define NSEG 16
#define SLQ 2048
#define SLH 2048

// Fragment-packed layouts (all produced in-kernel, consumed lane-linearly):
//  kb (per seg): unit (g*2+p) of 512 shorts; element (key g*16+l16,
//     col p*32+quad*8+j) at kb + seg*131072 + (g*2+p)*512 + lane*8 + j.
//  vt (per seg): unit ((kt*4+ks)*16+d16); element (dim d16*16+l16,
//     key kt*128+ks*32+quad*8+j) at vt + seg*524288 + unit*512 + lane*8 + j.
//  weights (WQ/WK/WV/fc_w): unit (n*8+ks); element (row n*16+l16,
//     col ks*32+quad*8+j) at w + ((n*8+ks)*64+lane)*8 + j.
// Ledger r0-r9: harness overhead C ≈ 89us, launch-count-independent (r7 3
// dispatches vs r9 1 dispatch: same C). Producer time real (~59us r7).
// r9 grid barrier cost ~40us (511 spinners, one cache line). r10 (this):
// per-SEGMENT 32-block barrier. A segment's 32 blocks all live on ONE XCD
// (seg=(b&7)*2+...), its K/V is 1.25MB -> fits the XCD's 4MB L2. Each block
// projects its own 64 tokens' K/V, arrives at its segment counter, overlaps
// the q-proj prologue with the wait, then runs flash on L2-resident K/V.
// 32 same-XCD spinners ≈ 10x cheaper than r9's grid barrier.

typedef __attribute__((ext_vector_type(8))) short bf16x8;
typedef __attribute__((ext_vector_type(8))) __bf16 bf16x8b;
typedef __attribute__((ext_vector_type(4))) float f32x4;
typedef __attribute__((ext_vector_type(4))) short s16x4;

// LDS-only barrier: completes this wave's LDS ops (lgkmcnt) and syncs, but does
// NOT drain outstanding global loads (vmcnt) the way __syncthreads() does.
#define BAR_LDS() asm volatile("s_waitcnt lgkmcnt(0)\n\ts_barrier" ::: "memory")

static __device__ __forceinline__ f32x4 mfma16(bf16x8 a, bf16x8 b, f32x4 c) {
  return __builtin_amdgcn_mfma_f32_16x16x32_bf16(
      __builtin_bit_cast(bf16x8b, a), __builtin_bit_cast(bf16x8b, b), c, 0, 0, 0);
}

static __device__ __forceinline__ short f2bf(float x) {
  union { float f; unsigned u; } v; v.f = x;
  unsigned r = v.u + 0x7fffu + ((v.u >> 16) & 1u);
  return (short)(r >> 16);
}

static __device__ __forceinline__ float bf2f(short s) {
  union { unsigned u; float f; } v;
  v.u = ((unsigned)(unsigned short)s) << 16;
  return v.f;
}

// Pack one weight element into fragment-linear order. i = packed short index.
static __device__ __forceinline__ void pack_w(const float* __restrict__ s,
                                              short* __restrict__ d, int i) {
  int j = i & 7, l16 = (i >> 3) & 15, quad = (i >> 7) & 3, ks = (i >> 9) & 7,
      n = i >> 12;
  d[i] = f2bf(s[(size_t)(n * 16 + l16) * HID + ks * 32 + quad * 8 + j]);
}

// Fused weight casts+packs: WQ, WK, WV, fc_w -> fragment-packed bf16
__global__ __launch_bounds__(256) void cast4_kernel(const float* __restrict__ s0, short* __restrict__ d0, int n0,
                                                    const float* __restrict__ s1, short* __restrict__ d1, int n1,
                                                    const float* __restrict__ s2, short* __restrict__ d2, int n2,
                                                    const float* __restrict__ s3, short* __restrict__ d3, int n3) {
  int i = blockIdx.x * 256 + threadIdx.x;
  if (i < n0) pack_w(s0, d0, i);
  int j = i - n0;
  if (j >= 0 && j < n1) pack_w(s1, d1, j);
  int k = j - n1;
  if (k >= 0 && k < n2) pack_w(s2, d2, k);
  int l = k - n2;
  if (l >= 0 && l < n3) pack_w(s3, d3, l);
}

// Fully-fused per-segment kernel: each block projects K/V for its own 64
// tokens -> segment barrier (32 same-XCD blocks) -> flash attn + LN0 + FC +
// LN1, with the q-proj prologue overlapping the barrier wait.
// 512 blocks x 512 threads, __launch_bounds__(512,4): 2 blocks/CU x 256 CU =
// entire grid co-resident by construction (spin-safe; proven r9).
__global__ __launch_bounds__(512, 4) void attn_kernel(
    const float* __restrict__ q, const float* __restrict__ h,
    const short* __restrict__ wqb, const short* __restrict__ wkb,
    const short* __restrict__ wvb, const short* __restrict__ fwb,
    const float* __restrict__ fcb, const float* __restrict__ n0w,
    const float* __restrict__ n0b, const float* __restrict__ n1w,
    const float* __restrict__ n1b, short* __restrict__ kb,
    short* __restrict__ vt, unsigned* __restrict__ bar,
    float* __restrict__ out) {
  __shared__ short p_lds[2][64][136];  // 34.8KB; A hb/vbuf alias; B staging/P/ob
  __shared__ short qx[4096];           // 8KB packed q-fragment bounce
  __shared__ float plsum[4][2][16];    // [qg][kh][row16] partial softmax sums
  __shared__ float rs[2][2][64];       // [s|s2][kh][row] LN1 partial sums

  int wave = threadIdx.x >> 6, lane = threadIdx.x & 63;
  int quad = lane >> 4, l16 = lane & 15;
  int b = blockIdx.x;
  int xcd = b & 7, li = b >> 3;
  int seg = xcd * 2 + (li >> 5);
  int tile = li & 31;
  int qrow0 = seg * SLQ + tile * 64;

  // ---------------- A: k/v projection of THIS block's 64 tokens ----------
  // (rows seg*2048 + tile*64 .. +64 — same-XCD L2 receives kb/vt writes)
  // 8 waves: wave&3 picks the 16-token slice; wave>>2 picks the V-dim half.
  // Waves 0-3 additionally compute the K projection.
  {
    short (*hb)[264] = (short(*)[264]) & p_lds[0][0][0];
    int m0 = seg * SLH + tile * 64;
#pragma unroll
    for (int i = 0; i < 8; ++i) {
      int idx = i * 512 + threadIdx.x;
      int row = idx >> 6, col = (idx & 63) * 4;
      f32x4 v = *(const f32x4*)(h + (size_t)(m0 + row) * HID + col);
      s16x4 pk;
#pragma unroll
      for (int j = 0; j < 4; ++j) pk[j] = f2bf(v[j]);
      *(s16x4*)&hb[row][col] = pk;
    }
    __syncthreads();
    int mw = (wave & 3) * 16;
    int mtb = (wave >> 2) * 8;
    f32x4 kacc[4];
    f32x4 vacc[8];
#pragma unroll
    for (int n = 0; n < 4; ++n) kacc[n] = f32x4{0.f, 0.f, 0.f, 0.f};
#pragma unroll
    for (int n = 0; n < 8; ++n) vacc[n] = f32x4{0.f, 0.f, 0.f, 0.f};
#pragma unroll
    for (int ks = 0; ks < 8; ++ks) {
      bf16x8 a = *(const bf16x8*)&hb[mw + l16][ks * 32 + quad * 8];
      if (wave < 4) {
#pragma unroll
        for (int n = 0; n < 4; ++n) {
          bf16x8 wb = *(const bf16x8*)(wkb + (size_t)((n * 8 + ks) * 64 + lane) * 8);
          kacc[n] = mfma16(a, wb, kacc[n]);
        }
      }
#pragma unroll
      for (int mt = 0; mt < 8; ++mt) {
        bf16x8 wf = *(const bf16x8*)(wvb + (size_t)(((mtb + mt) * 8 + ks) * 64 + lane) * 8);
        vacc[mt] = mfma16(wf, a, vacc[mt]);  // D[m=dv][n=tok] = WV @ h^T
      }
    }
    __syncthreads();  // ALL waves' hb reads done before bounce writes rows
    if (wave < 4) {
      // packed kb write; bounce in this wave's own (now dead) hb rows
      char* kx = (char*)&hb[mw][0];
#pragma unroll
      for (int n = 0; n < 4; ++n)
#pragma unroll
        for (int r = 0; r < 4; ++r) {
          int k16 = quad * 4 + r;
          int bo = (k16 * 128 + (n * 16 + l16) * 2) ^ ((k16 & 7) << 4);
          *(short*)(kx + bo) = f2bf(kacc[n][r]);
        }
      asm volatile("s_waitcnt lgkmcnt(0)" ::: "memory");
      int g = (tile * 64 + mw) >> 4;
      short* kdst = kb + (size_t)seg * 131072 + (size_t)g * 1024 + lane * 8;
#pragma unroll
      for (int p = 0; p < 2; ++p) {
        int bo = (l16 * 128 + p * 64 + quad * 16) ^ ((l16 & 7) << 4);
        *(bf16x8*)(kdst + p * 512) = *(bf16x8*)(kx + bo);
      }
    }
    __syncthreads();  // bounce reads drained -> safe to reuse hb as vbuf
    {
      char* vbuf = (char*)&hb[0][0];  // 32KB
#pragma unroll
      for (int mt = 0; mt < 8; ++mt)
#pragma unroll
        for (int r = 0; r < 4; ++r) {
          int dv = (mtb + mt) * 16 + quad * 4 + r;
          int bo = (dv * 128 + (mw + l16) * 2) ^ ((dv & 7) << 4);
          *(short*)(vbuf + bo) = f2bf(vacc[mt][r]);
        }
      __syncthreads();
      // packed vt write-out: 32 units of 1KB; 4 per wave, fully coalesced
      int t0 = tile * 64;
      int kt = t0 >> 7;
      int ksb = (t0 >> 5) & 3;  // 0 or 2 (tiles are 64-token aligned)
      short* vdst = vt + (size_t)seg * 524288;
#pragma unroll
      for (int i = 0; i < 4; ++i) {
        int u = wave * 4 + i;
        int ksl = u >> 4, d16 = u & 15;
        int dim = d16 * 16 + l16;
        int bo = (dim * 128 + ksl * 64 + quad * 16) ^ ((dim & 7) << 4);
        size_t unit = (size_t)((kt * 4 + ksb + ksl) * 16 + d16);
        *(bf16x8*)(vdst + unit * 512 + lane * 8) = *(bf16x8*)(vbuf + bo);
      }
    }
  }

  // ---- segment-barrier ARRIVE (stores drained by __syncthreads) ----
  __syncthreads();
  if (threadIdx.x == 0) {
    __threadfence();
    atomicAdd(&bar[seg * 32], 1u);
  }

  // ---- q-proj prologue (overlaps other blocks' A-phase) ----
  int qg = wave >> 1, kh = wave & 1;
  short (*st)[264] = (short(*)[264]) & p_lds[0][0][0];
  bf16x8 qf0, qf1;
  {
    const float* qsrc = q + (size_t)qrow0 * HID;
#pragma unroll
    for (int i = 0; i < 8; ++i) {
      int idx = i * 512 + threadIdx.x;
      int row = idx >> 6, col = (idx & 63) * 4;
      f32x4 v = *(const f32x4*)(qsrc + (size_t)row * HID + col);
      s16x4 pk;
#pragma unroll
      for (int j = 0; j < 4; ++j) pk[j] = f2bf(v[j]);
      *(s16x4*)&st[row][col] = pk;
    }
    __syncthreads();
    f32x4 qacc[2];
    qacc[0] = f32x4{0.f, 0.f, 0.f, 0.f};
    qacc[1] = f32x4{0.f, 0.f, 0.f, 0.f};
#pragma unroll
    for (int ks = 0; ks < 8; ++ks) {
      bf16x8 a = *(const bf16x8*)&st[qg * 16 + l16][ks * 32 + quad * 8];
#pragma unroll
      for (int ni = 0; ni < 2; ++ni) {
        int n = kh * 2 + ni;
        bf16x8 wb = *(const bf16x8*)(wqb + (size_t)((n * 8 + ks) * 64 + lane) * 8);
        qacc[ni] = mfma16(a, wb, qacc[ni]);
      }
    }
    BAR_LDS();  // all st reads done block-wide before S_PHASE may overwrite
#pragma unroll
    for (int ni = 0; ni < 2; ++ni)
#pragma unroll
      for (int r = 0; r < 4; ++r) {
        int n = kh * 2 + ni;
        int colp = (n & 1) * 16 + l16;
        qx[(qg * 2 + (n >> 1)) * 512 + ((colp >> 3) * 16 + quad * 4 + r) * 8 +
           (colp & 7)] = f2bf(qacc[ni][r]);
      }
    BAR_LDS();
    const short* qxp = qx + qg * 1024 + lane * 8;
    qf0 = *(const bf16x8*)qxp;
    qf1 = *(const bf16x8*)(qxp + 512);
  }

  // ---- segment-barrier WAIT (32 same-XCD blocks; thread 0 spins) ----
  if (threadIdx.x == 0) {
    while (atomicAdd(&bar[seg * 32], 0u) < 32u) __builtin_amdgcn_s_sleep(2);
    __threadfence();
  }
  __syncthreads();

  // ---------------- B: flash attention (r7 code) ----------------
  const short* kseg = kb + (size_t)seg * 131072;
  const short* vseg = vt + (size_t)seg * 524288;
  const float cexp = 0.125f * 1.44269504f;  // scale * log2(e)
  bf16x8 kpre[4][2];

#define LOADK(KT)                                                               \
  {                                                                             \
    _Pragma("unroll") for (int t = 0; t < 4; ++t) {                             \
      const short* kp = kseg + (size_t)((KT) * 8 + kh * 4 + t) * 1024 + lane * 8;\
      kpre[t][0] = *(const bf16x8*)kp;                                          \
      kpre[t][1] = *(const bf16x8*)(kp + 512);                                  \
    }                                                                           \
  }

  f32x4 o[4][2];  // [qrow-group m][dim-group n]: 64 rows x 32 dims per wave
#pragma unroll
  for (int m = 0; m < 4; ++m)
#pragma unroll
    for (int n = 0; n < 2; ++n) o[m][n] = f32x4{0.f, 0.f, 0.f, 0.f};
  float lsum = 0.f;

#define S_PHASE(BUF)                                                            \
  {                                                                             \
    f32x4 s[4];                                                                 \
    _Pragma("unroll") for (int t = 0; t < 4; ++t) {                             \
      f32x4 a = f32x4{0.f, 0.f, 0.f, 0.f};                                      \
      a = mfma16(kpre[t][0], qf0, a);                                           \
      a = mfma16(kpre[t][1], qf1, a);                                           \
      s[t] = a;                                                                 \
    }                                                                           \
    _Pragma("unroll") for (int t = 0; t < 4; ++t) {                             \
      float p0 = __builtin_amdgcn_exp2f(s[t][0] * cexp);                        \
      float p1 = __builtin_amdgcn_exp2f(s[t][1] * cexp);                        \
      float p2 = __builtin_amdgcn_exp2f(s[t][2] * cexp);                        \
      float p3 = __builtin_amdgcn_exp2f(s[t][3] * cexp);                        \
      lsum += (p0 + p1) + (p2 + p3);                                            \
      s16x4 pk;                                                                 \
      pk[0] = f2bf(p0); pk[1] = f2bf(p1); pk[2] = f2bf(p2); pk[3] = f2bf(p3);   \
      *(s16x4*)&p_lds[BUF][qg * 16 + l16][kh * 64 + t * 16 + quad * 4] = pk;    \
    }                                                                           \
  }

#define PV_PHASE(KT, BUF)                                                       \
  {                                                                             \
    _Pragma("unroll") for (int ks = 0; ks < 4; ++ks) {                          \
      bf16x8 pf[4];                                                             \
      _Pragma("unroll") for (int m = 0; m < 4; ++m)                             \
        pf[m] = *(const bf16x8*)&p_lds[BUF][m * 16 + l16][ks * 32 + quad * 8];  \
      _Pragma("unroll") for (int n = 0; n < 2; ++n) {                           \
        const short* vp = vseg +                                                \
            ((size_t)((KT) * 4 + ks) * 16 + wave * 2 + n) * 512 + lane * 8;     \
        bf16x8 vf = *(const bf16x8*)vp;                                         \
        _Pragma("unroll") for (int m = 0; m < 4; ++m)                           \
          o[m][n] = mfma16(pf[m], vf, o[m][n]);                                 \
      }                                                                         \
    }                                                                           \
  }

  // staggered key-tile order (r2, kept): block at q-tile `tile` starts at tile&15
  LOADK(tile & 15)
  S_PHASE(0)
  LOADK((tile + 1) & 15)
  BAR_LDS();
#pragma unroll 1
  for (int j = 1; j < 16; ++j) {
    S_PHASE(j & 1)
    if (j < 15) LOADK((tile + j + 1) & 15)
    PV_PHASE((tile + j - 1) & 15, (j - 1) & 1)
    BAR_LDS();
  }
  PV_PHASE((tile + 15) & 15, 1)

  // per-wave lsum: reduce over quads -> lane l16 holds this wave's partial
  lsum += __shfl_xor(lsum, 16);
  lsum += __shfl_xor(lsum, 32);

  BAR_LDS();  // all PV LDS reads done before o-staging overwrites p_lds
  if (lane < 16) plsum[qg][kh][lane] = lsum;
  short (*ob)[264] = (short(*)[264]) & p_lds[0][0][0];
#pragma unroll
  for (int m = 0; m < 4; ++m)
#pragma unroll
    for (int n = 0; n < 2; ++n)
#pragma unroll
      for (int r = 0; r < 4; ++r)
        ob[m * 16 + quad * 4 + r][wave * 32 + n * 16 + l16] = f2bf(o[m][n][r]);
  BAR_LDS();

  // ---- LN0 (x written in-place into ob) ----
  {
    int row = wave * 8 + (lane >> 3);
    int c0 = (lane & 7) * 32;
    float linv = 1.f / (plsum[row >> 4][0][row & 15] + plsum[row >> 4][1][row & 15]);
    float y[32];
    float s1 = 0.f, s2 = 0.f;
    const float* qp = q + (size_t)(qrow0 + row) * HID + c0;
#pragma unroll
    for (int k = 0; k < 4; ++k) {
      bf16x8 ov = *(const bf16x8*)&ob[row][c0 + k * 8];
      f32x4 qa = *(const f32x4*)(qp + k * 8);
      f32x4 qb = *(const f32x4*)(qp + k * 8 + 4);
#pragma unroll
      for (int j = 0; j < 4; ++j) {
        float yv = qa[j] + bf2f(ov[j]) * linv;
        y[k * 8 + j] = yv;
        s1 += yv; s2 += yv * yv;
      }
#pragma unroll
      for (int j = 0; j < 4; ++j) {
        float yv = qb[j] + bf2f(ov[4 + j]) * linv;
        y[k * 8 + 4 + j] = yv;
        s1 += yv; s2 += yv * yv;
      }
    }
    s1 += __shfl_xor(s1, 1); s2 += __shfl_xor(s2, 1);
    s1 += __shfl_xor(s1, 2); s2 += __shfl_xor(s2, 2);
    s1 += __shfl_xor(s1, 4); s2 += __shfl_xor(s2, 4);
    float mean = s1 * (1.f / HID);
    float var = s2 * (1.f / HID) - mean * mean;
    float rstd = rsqrtf(var + 1e-5f);
#pragma unroll
    for (int k = 0; k < 4; ++k) {
      f32x4 wa = *(const f32x4*)(n0w + c0 + k * 8);
      f32x4 wb = *(const f32x4*)(n0w + c0 + k * 8 + 4);
      f32x4 ba = *(const f32x4*)(n0b + c0 + k * 8);
      f32x4 bb = *(const f32x4*)(n0b + c0 + k * 8 + 4);
      s16x4 o0, o1;
#pragma unroll
      for (int j = 0; j < 4; ++j) {
        o0[j] = f2bf((y[k * 8 + j] - mean) * rstd * wa[j] + ba[j]);
        o1[j] = f2bf((y[k * 8 + 4 + j] - mean) * rstd * wb[j] + bb[j]);
      }
      // in-place: this thread exclusively owns (row, c0..c0+31)
      *(s16x4*)&ob[row][c0 + k * 8] = o0;
      *(s16x4*)&ob[row][c0 + k * 8 + 4] = o1;
    }
  }
  BAR_LDS();  // x tile complete and visible

  // ---- FC GEMM + LN1 ----
  {
    f32x4 facc[8];
#pragma unroll
    for (int n2 = 0; n2 < 8; ++n2) facc[n2] = f32x4{0.f, 0.f, 0.f, 0.f};
#pragma unroll
    for (int ks = 0; ks < 8; ++ks) {
      bf16x8 a = *(const bf16x8*)&ob[qg * 16 + l16][ks * 32 + quad * 8];
#pragma unroll
      for (int n2 = 0; n2 < 8; ++n2) {
        int n = kh * 8 + n2;
        bf16x8 wb = *(const bf16x8*)(fwb + (size_t)((n * 8 + ks) * 64 + lane) * 8);
        facc[n2] = mfma16(a, wb, facc[n2]);
      }
    }
#pragma unroll
    for (int r = 0; r < 4; ++r) {
      int row = qg * 16 + quad * 4 + r;
      float s = 0.f, s2 = 0.f;
#pragma unroll
      for (int n2 = 0; n2 < 8; ++n2) {
        int col = kh * 128 + n2 * 16 + l16;
        float hres = fmaxf(facc[n2][r] + fcb[col], 0.f);
        float yv = bf2f(ob[row][col]) + hres;
        s += yv; s2 += yv * yv;
      }
      s += __shfl_xor(s, 1); s2 += __shfl_xor(s2, 1);
      s += __shfl_xor(s, 2); s2 += __shfl_xor(s2, 2);
      s += __shfl_xor(s, 4); s2 += __shfl_xor(s2, 4);
      s += __shfl_xor(s, 8); s2 += __shfl_xor(s2, 8);
      if (l16 == 0) { rs[0][kh][row] = s; rs[1][kh][row] = s2; }
    }
    BAR_LDS();
#pragma unroll
    for (int r = 0; r < 4; ++r) {
      int row = qg * 16 + quad * 4 + r;
      float st1 = rs[0][0][row] + rs[0][1][row];
      float st2 = rs[1][0][row] + rs[1][1][row];
      float mean = st1 * (1.f / HID);
      float var = st2 * (1.f / HID) - mean * mean;
      float rstd = rsqrtf(var + 1e-5f);
      float* op = out + (size_t)(qrow0 + row) * HID;
#pragma unroll
      for (int n2 = 0; n2 < 8; ++n2) {
        int col = kh * 128 + n2 * 16 + l16;
        float hres = fmaxf(facc[n2][r] + fcb[col], 0.f);
        float yv = bf2f(ob[row][col]) + hres;
        op[col] = (yv - mean) * rstd * n1w[col] + n1b[col];
      }
    }
  }
#undef LOADK
#undef S_PHASE
#undef PV_PHASE
}

extern "C" void kernel_launch(void* const* d_in, const int* in_sizes, int n_in,
                              void* d_out, int out_size, void* d_ws, size_t ws_size,
                              hipStream_t stream) {
  const float* q = (const float*)d_in[0];
  const float* h = (const float*)d_in[1];
  const float* WQ = (const float*)d_in[2];
  const float* WK = (const float*)d_in[3];
  const float* WV = (const float*)d_in[4];
  const float* fc_w = (const float*)d_in[5];
  const float* fc_b = (const float*)d_in[6];
  const float* n0w = (const float*)d_in[7];
  const float* n0b = (const float*)d_in[8];
  const float* n1w = (const float*)d_in[9];
  const float* n1b = (const float*)d_in[10];

  char* ws = (char*)d_ws;
  short* kb = (short*)(ws);                            //  4 MB  [0,4)  packed
  short* vt = (short*)(ws + ((size_t)4 << 20));        // 16 MB  [4,20) packed
  short* wqb = (short*)(ws + ((size_t)20 << 20));
  short* wkb = (short*)(ws + ((size_t)20 << 20) + 32 * 1024);
  short* wvb = (short*)(ws + ((size_t)20 << 20) + 64 * 1024);
  short* fwb = (short*)(ws + ((size_t)20 << 20) + 192 * 1024);
  unsigned* bar = (unsigned*)(ws + ((size_t)21 << 20));  // per-seg counters

  hipMemsetAsync(bar, 0, 16 * 32 * sizeof(unsigned), stream);
  cast4_kernel<<<640, 256, 0, stream>>>(WQ, wqb, QD * HID, WK, wkb, QD * HID,
                                        WV, wvb, HID * HID, fc_w, fwb, HID * HID);
  attn_kernel<<<512, 512, 0, stream>>>(q, h, wqb, wkb, wvb, fwb, fc_b,
                                       n0w, n0b, n1w, n1b, kb, vt, bar,
                                       (float*)d_out);
}

// Round 11
// 240.090 us; speedup vs baseline: 1.1916x; 1.0531x over previous
//
#include <hip/hip_runtime.h>
#include <hip/hip_bf16.h>

#define HID 256
#define QD 64
#define NSEG 16
#define SLQ 2048
#define SLH 2048

// Fragment-packed layouts (all produced by us, consumed lane-linearly):
//  kb (per seg): unit (g*2+p) of 512 shorts; element (key g*16+l16,
//     col p*32+quad*8+j) at kb + seg*131072 + (g*2+p)*512 + lane*8 + j.
//  vt (per seg): unit ((kt4*4... unit u = key16group-pair) — element (dim
//     d16*16+l16, key u32*32+quad*8+j) at vt + seg*524288 + (u32*16+d16)*512
//     + lane*8 + j, where u32 indexes 32-key slices.
//  weights (WQ/WK/WV/fc_w): unit (n*8+ks); element (row n*16+l16,
//     col ks*32+quad*8+j) at w + ((n*8+ks)*64+lane)*8 + j.
// Ledger (r0-r10): harness overhead C≈89us fixed & launch-count-independent;
// best structure = r7 3-kernel (245.2us): cast4(~8) + proj_kv(~51) + attn(97).
// r11 (this): T3/T4 counted-vmcnt pipeline on attn's V path. K was already
// reg-prefetched 1 iter ahead; V was IN-PHASE (load->immediate MFMA, the last
// un-hidden latency; r3 showed reg-prefetch of V spills at the compiler's
// 64-VGPR choice). Fix costs 0 VGPRs: V prefetched 1 iter ahead via
// global_load_lds into a WAVE-PRIVATE single LDS buffer (each wave gll-loads
// exactly the 4 units only it reads -> no cross-wave hazard), guarded by
// s_waitcnt vmcnt(4) (drains oldest = V(j-1); leaves K(j+1) in flight).
// KVBLK halved to 64 (32 iters) so LDS = P 18KB + V 32KB + misc = 75.5KB
// -> 2 blocks/CU kept.

typedef __attribute__((ext_vector_type(8))) short bf16x8;
typedef __attribute__((ext_vector_type(8))) __bf16 bf16x8b;
typedef __attribute__((ext_vector_type(4))) float f32x4;
typedef __attribute__((ext_vector_type(4))) short s16x4;

// LDS-only barrier: completes this wave's LDS ops (lgkmcnt) and syncs, but does
// NOT drain outstanding global loads (vmcnt) the way __syncthreads() does.
#define BAR_LDS() asm volatile("s_waitcnt lgkmcnt(0)\n\ts_barrier" ::: "memory")

static __device__ __forceinline__ f32x4 mfma16(bf16x8 a, bf16x8 b, f32x4 c) {
  return __builtin_amdgcn_mfma_f32_16x16x32_bf16(
      __builtin_bit_cast(bf16x8b, a), __builtin_bit_cast(bf16x8b, b), c, 0, 0, 0);
}

static __device__ __forceinline__ short f2bf(float x) {
  union { float f; unsigned u; } v; v.f = x;
  unsigned r = v.u + 0x7fffu + ((v.u >> 16) & 1u);
  return (short)(r >> 16);
}

static __device__ __forceinline__ float bf2f(short s) {
  union { unsigned u; float f; } v;
  v.u = ((unsigned)(unsigned short)s) << 16;
  return v.f;
}

// Pack one weight element into fragment-linear order. i = packed short index.
static __device__ __forceinline__ void pack_w(const float* __restrict__ s,
                                              short* __restrict__ d, int i) {
  int j = i & 7, l16 = (i >> 3) & 15, quad = (i >> 7) & 3, ks = (i >> 9) & 7,
      n = i >> 12;
  d[i] = f2bf(s[(size_t)(n * 16 + l16) * HID + ks * 32 + quad * 8 + j]);
}

// Fused weight casts+packs: WQ, WK, WV, fc_w -> fragment-packed bf16
__global__ __launch_bounds__(256) void cast4_kernel(const float* __restrict__ s0, short* __restrict__ d0, int n0,
                                                    const float* __restrict__ s1, short* __restrict__ d1, int n1,
                                                    const float* __restrict__ s2, short* __restrict__ d2, int n2,
                                                    const float* __restrict__ s3, short* __restrict__ d3, int n3) {
  int i = blockIdx.x * 256 + threadIdx.x;
  if (i < n0) pack_w(s0, d0, i);
  int j = i - n0;
  if (j >= 0 && j < n1) pack_w(s1, d1, j);
  int k = j - n1;
  if (k >= 0 && k < n2) pack_w(s2, d2, k);
  int l = k - n2;
  if (l >= 0 && l < n3) pack_w(s3, d3, l);
}

// k = h @ WK^T -> kb (fragment-packed); v^T = WV @ h^T -> vt (fragment-packed).
// (r7 verbatim — best-known producer configuration.)
__global__ __launch_bounds__(256, 4) void proj_kv_kernel(const float* __restrict__ h,
                                                         const short* __restrict__ wkb,
                                                         const short* __restrict__ wvb,
                                                         short* __restrict__ kb,
                                                         short* __restrict__ vt) {
  __shared__ short hb[64][264];  // staging; per-wave bounce; reused as vbuf
  int wave = threadIdx.x >> 6, lane = threadIdx.x & 63;
  int quad = lane >> 4, l16 = lane & 15;
  int mw = wave * 16;
  int m0 = blockIdx.x * 64;
#pragma unroll
  for (int i = 0; i < 16; ++i) {
    int idx = i * 256 + threadIdx.x;
    int row = idx >> 6, col = (idx & 63) * 4;
    f32x4 v = *(const f32x4*)(h + (size_t)(m0 + row) * HID + col);
    s16x4 pk;
#pragma unroll
    for (int j = 0; j < 4; ++j) pk[j] = f2bf(v[j]);
    *(s16x4*)&hb[row][col] = pk;
  }
  __syncthreads();
  f32x4 kacc[4];
  f32x4 vacc[16];
#pragma unroll
  for (int n = 0; n < 4; ++n) kacc[n] = f32x4{0.f, 0.f, 0.f, 0.f};
#pragma unroll
  for (int n = 0; n < 16; ++n) vacc[n] = f32x4{0.f, 0.f, 0.f, 0.f};
#pragma unroll
  for (int ks = 0; ks < 8; ++ks) {
    bf16x8 a = *(const bf16x8*)&hb[mw + l16][ks * 32 + quad * 8];
#pragma unroll
    for (int n = 0; n < 4; ++n) {
      bf16x8 b = *(const bf16x8*)(wkb + (size_t)((n * 8 + ks) * 64 + lane) * 8);
      kacc[n] = mfma16(a, b, kacc[n]);
    }
#pragma unroll
    for (int mt = 0; mt < 16; ++mt) {
      bf16x8 wf = *(const bf16x8*)(wvb + (size_t)((mt * 8 + ks) * 64 + lane) * 8);
      vacc[mt] = mfma16(wf, a, vacc[mt]);  // D[m=dv][n=tok] = WV @ h^T
    }
  }
  // packed kb write; bounce in this wave's own (now dead) hb rows
  {
    char* kx = (char*)&hb[mw][0];  // 4KB window, stays inside wave's 16 rows
#pragma unroll
    for (int n = 0; n < 4; ++n)
#pragma unroll
      for (int r = 0; r < 4; ++r) {
        int k16 = quad * 4 + r;
        int bo = (k16 * 128 + (n * 16 + l16) * 2) ^ ((k16 & 7) << 4);
        *(short*)(kx + bo) = f2bf(kacc[n][r]);
      }
    asm volatile("s_waitcnt lgkmcnt(0)" ::: "memory");
    int seg = (m0 + mw) >> 11;
    int g = ((m0 + mw) & 2047) >> 4;
    short* kdst = kb + (size_t)seg * 131072 + (size_t)g * 1024 + lane * 8;
#pragma unroll
    for (int p = 0; p < 2; ++p) {
      int bo = (l16 * 128 + p * 64 + quad * 16) ^ ((l16 & 7) << 4);
      *(bf16x8*)(kdst + p * 512) = *(bf16x8*)(kx + bo);
    }
  }
  __syncthreads();  // kb bounce reads drained -> safe to reuse hb as vbuf
  // assemble V^T tile (256 dims x 64 toks) in swizzled vbuf, then write out
  {
    char* vbuf = (char*)&hb[0][0];  // 32KB of the 33.8KB buffer
#pragma unroll
    for (int mt = 0; mt < 16; ++mt)
#pragma unroll
      for (int r = 0; r < 4; ++r) {
        int dv = mt * 16 + quad * 4 + r;
        int bo = (dv * 128 + (mw + l16) * 2) ^ ((dv & 7) << 4);
        *(short*)(vbuf + bo) = f2bf(vacc[mt][r]);
      }
    __syncthreads();
    // packed vt write-out: 32 units of 1KB; 8 per wave, fully coalesced
    int seg = m0 >> 11;
    int t0 = m0 & 2047;
    int kt = t0 >> 7;
    int ksb = (t0 >> 5) & 3;  // 0 or 2 (blocks are 64-token aligned)
    short* vdst = vt + (size_t)seg * 524288;
#pragma unroll
    for (int i = 0; i < 8; ++i) {
      int u = wave * 8 + i;
      int ksl = u >> 4, d16 = u & 15;
      int dim = d16 * 16 + l16;
      int bo = (dim * 128 + ksl * 64 + quad * 16) ^ ((dim & 7) << 4);
      size_t unit = (size_t)((kt * 4 + ksb + ksl) * 16 + d16);
      *(bf16x8*)(vdst + unit * 512 + lane * 8) = *(bf16x8*)(vbuf + bo);
    }
  }
}

// Flash attention v10 + fused q-proj + LN0 + FC + LN1. 8-wave blocks, grid 512.
// KVBLK=64 (32 iters). K reg-prefetched 1 iter ahead; V prefetched 1 iter
// ahead via global_load_lds into a wave-private single LDS buffer, guarded by
// counted vmcnt(4) (retires oldest = V(j-1), leaves K(j+1) in flight; sound
// per oldest-first vmcnt semantics regardless of compiler load placement).
__global__ __launch_bounds__(512, 4) void attn_kernel(const float* __restrict__ q,
                                                      const short* __restrict__ wqb,
                                                      const short* __restrict__ kb,
                                                      const short* __restrict__ vt,
                                                      const short* __restrict__ fwb,
                                                      const float* __restrict__ fcb,
                                                      const float* __restrict__ n0w,
                                                      const float* __restrict__ n0b,
                                                      const float* __restrict__ n1w,
                                                      const float* __restrict__ n1b,
                                                      float* __restrict__ out) {
  // arena: [0..33792) = q-staging (prologue) / P dbuf [2][64][72] (loop, 18.4KB)
  //        / ob [64][264] (epilogue).  [34816..67584) = wave-private V buffer.
  __shared__ __align__(16) char arena_c[67584];
  __shared__ short qx[4096];           // 8KB packed q-fragment bounce
  __shared__ float plsum[4][2][16];    // [qg][kh][row16] partial softmax sums
  __shared__ float rs[2][2][64];       // [s|s2][kh][row] LN1 partial sums
  short (*p_lds)[64][72] = (short(*)[64][72])arena_c;
  short* v_lds = (short*)(arena_c + 34816);

  int wave = threadIdx.x >> 6, lane = threadIdx.x & 63;
  int quad = lane >> 4, l16 = lane & 15;
  int qg = wave >> 1, kh = wave & 1;
  int b = blockIdx.x;
  int xcd = b & 7, li = b >> 3;
  int seg = xcd * 2 + (li >> 5);
  int tile = li & 31;
  int qrow0 = seg * SLQ + tile * 64;
  const short* kseg = kb + (size_t)seg * 131072;
  const short* vseg = vt + (size_t)seg * 524288;

  const float cexp = 0.125f * 1.44269504f;  // scale * log2(e)
  bf16x8 kpre[2][2];

// staggered 64-key tile order (r2): block at q-tile `tile` starts at tile*2
#define KT2_(J) ((tile * 2 + (J)) & 31)

#define LOADK(KT2)                                                              \
  {                                                                             \
    _Pragma("unroll") for (int t = 0; t < 2; ++t) {                             \
      const short* kp =                                                         \
          kseg + (size_t)((KT2) * 4 + kh * 2 + t) * 1024 + lane * 8;            \
      kpre[t][0] = *(const bf16x8*)kp;                                          \
      kpre[t][1] = *(const bf16x8*)(kp + 512);                                  \
    }                                                                           \
  }

// wave-private V prefetch: each wave gll-loads exactly the 4 1KB units that
// only it will ds_read next iteration (units (ks, wave*2+n)).
#define VGLL(KT2)                                                               \
  {                                                                             \
    _Pragma("unroll") for (int ks = 0; ks < 2; ++ks)                            \
      _Pragma("unroll") for (int n = 0; n < 2; ++n) {                           \
        const short* vp = vseg +                                                \
            ((size_t)((KT2) * 2 + ks) * 16 + wave * 2 + n) * 512 + lane * 8;    \
        short* lp = v_lds + (((ks * 16 + wave * 2 + n) << 9));                  \
        __builtin_amdgcn_global_load_lds(                                       \
            (const __attribute__((address_space(1))) unsigned int*)vp,          \
            (__attribute__((address_space(3))) unsigned int*)lp, 16, 0, 0);     \
      }                                                                         \
  }

// vmcnt(4): retire everything except the 4 newest vmem ops (= K(j+1));
// guarantees V(j-1)'s 4 gll ops (issued before K(j+1)) have landed.
#define GUARD_V() asm volatile("s_waitcnt vmcnt(4)" ::: "memory")

#define S_PHASE(BUF)                                                            \
  {                                                                             \
    f32x4 s[2];                                                                 \
    _Pragma("unroll") for (int t = 0; t < 2; ++t) {                             \
      f32x4 a = f32x4{0.f, 0.f, 0.f, 0.f};                                      \
      a = mfma16(kpre[t][0], qf0, a);                                           \
      a = mfma16(kpre[t][1], qf1, a);                                           \
      s[t] = a;                                                                 \
    }                                                                           \
    _Pragma("unroll") for (int t = 0; t < 2; ++t) {                             \
      float p0 = __builtin_amdgcn_exp2f(s[t][0] * cexp);                        \
      float p1 = __builtin_amdgcn_exp2f(s[t][1] * cexp);                        \
      float p2 = __builtin_amdgcn_exp2f(s[t][2] * cexp);                        \
      float p3 = __builtin_amdgcn_exp2f(s[t][3] * cexp);                        \
      lsum += (p0 + p1) + (p2 + p3);                                            \
      s16x4 pk;                                                                 \
      pk[0] = f2bf(p0); pk[1] = f2bf(p1); pk[2] = f2bf(p2); pk[3] = f2bf(p3);   \
      *(s16x4*)&p_lds[BUF][qg * 16 + l16][kh * 32 + t * 16 + quad * 4] = pk;    \
    }                                                                           \
  }

#define PV_PHASE(BUF)                                                           \
  {                                                                             \
    _Pragma("unroll") for (int ks = 0; ks < 2; ++ks) {                          \
      bf16x8 pf[4];                                                             \
      _Pragma("unroll") for (int m = 0; m < 4; ++m)                             \
        pf[m] = *(const bf16x8*)&p_lds[BUF][m * 16 + l16][ks * 32 + quad * 8];  \
      _Pragma("unroll") for (int n = 0; n < 2; ++n) {                           \
        bf16x8 vf = *(const bf16x8*)(v_lds +                                    \
            ((ks * 16 + wave * 2 + n) << 9) + lane * 8);                        \
        _Pragma("unroll") for (int m = 0; m < 4; ++m)                           \
          o[m][n] = mfma16(pf[m], vf, o[m][n]);                                 \
      }                                                                         \
    }                                                                           \
  }

  // first K-tile + V-tile flights overlap the q-proj prologue
  LOADK(KT2_(0))
  VGLL(KT2_(0))

  // ---- prologue: q projection (staging in arena bytes 0..33792) ----
  short (*st)[264] = (short(*)[264])arena_c;
  bf16x8 qf0, qf1;
  {
    const float* qsrc = q + (size_t)qrow0 * HID;
#pragma unroll
    for (int i = 0; i < 8; ++i) {
      int idx = i * 512 + threadIdx.x;
      int row = idx >> 6, col = (idx & 63) * 4;
      f32x4 v = *(const f32x4*)(qsrc + (size_t)row * HID + col);
      s16x4 pk;
#pragma unroll
      for (int j = 0; j < 4; ++j) pk[j] = f2bf(v[j]);
      *(s16x4*)&st[row][col] = pk;
    }
    __syncthreads();
    f32x4 qacc[2];
    qacc[0] = f32x4{0.f, 0.f, 0.f, 0.f};
    qacc[1] = f32x4{0.f, 0.f, 0.f, 0.f};
#pragma unroll
    for (int ks = 0; ks < 8; ++ks) {
      bf16x8 a = *(const bf16x8*)&st[qg * 16 + l16][ks * 32 + quad * 8];
#pragma unroll
      for (int ni = 0; ni < 2; ++ni) {
        int n = kh * 2 + ni;
        bf16x8 wb = *(const bf16x8*)(wqb + (size_t)((n * 8 + ks) * 64 + lane) * 8);
        qacc[ni] = mfma16(a, wb, qacc[ni]);
      }
    }
    BAR_LDS();  // all st reads done block-wide before S_PHASE may overwrite
#pragma unroll
    for (int ni = 0; ni < 2; ++ni)
#pragma unroll
      for (int r = 0; r < 4; ++r) {
        int n = kh * 2 + ni;
        int colp = (n & 1) * 16 + l16;
        qx[(qg * 2 + (n >> 1)) * 512 + ((colp >> 3) * 16 + quad * 4 + r) * 8 +
           (colp & 7)] = f2bf(qacc[ni][r]);
      }
    BAR_LDS();
    const short* qxp = qx + qg * 1024 + lane * 8;
    qf0 = *(const bf16x8*)qxp;
    qf1 = *(const bf16x8*)(qxp + 512);
  }

  f32x4 o[4][2];  // [qrow-group m][dim-group n]: 64 rows x 32 dims per wave
#pragma unroll
  for (int m = 0; m < 4; ++m)
#pragma unroll
    for (int n = 0; n < 2; ++n) o[m][n] = f32x4{0.f, 0.f, 0.f, 0.f};
  float lsum = 0.f;

  S_PHASE(0)
  LOADK(KT2_(1))
  BAR_LDS();
#pragma unroll 1
  for (int j = 1; j < 32; ++j) {
    S_PHASE(j & 1)
    if (j < 31) LOADK(KT2_(j + 1))
    GUARD_V();                         // V(j-1) landed; K(j+1) stays in flight
    PV_PHASE((j - 1) & 1)              // ds_read own V units + P, MFMA
    __builtin_amdgcn_sched_barrier(0); // pin: VGLL must not hoist above PV reads
    VGLL(KT2_(j))                      // refill own units for next iter's PV
    BAR_LDS();
  }
  asm volatile("s_waitcnt vmcnt(0)" ::: "memory");
  PV_PHASE(1)                          // j=31 tile, buf 31&1

  // per-wave lsum: reduce over quads -> lane l16 holds this wave's partial
  lsum += __shfl_xor(lsum, 16);
  lsum += __shfl_xor(lsum, 32);

  BAR_LDS();  // all PV LDS reads done before o-staging overwrites arena
  if (lane < 16) plsum[qg][kh][lane] = lsum;
  short (*ob)[264] = (short(*)[264])arena_c;
#pragma unroll
  for (int m = 0; m < 4; ++m)
#pragma unroll
    for (int n = 0; n < 2; ++n)
#pragma unroll
      for (int r = 0; r < 4; ++r)
        ob[m * 16 + quad * 4 + r][wave * 32 + n * 16 + l16] = f2bf(o[m][n][r]);
  BAR_LDS();

  // ---- LN0 (x written in-place into ob) ----
  {
    int row = wave * 8 + (lane >> 3);
    int c0 = (lane & 7) * 32;
    float linv = 1.f / (plsum[row >> 4][0][row & 15] + plsum[row >> 4][1][row & 15]);
    float y[32];
    float s1 = 0.f, s2 = 0.f;
    const float* qp = q + (size_t)(qrow0 + row) * HID + c0;
#pragma unroll
    for (int k = 0; k < 4; ++k) {
      bf16x8 ov = *(const bf16x8*)&ob[row][c0 + k * 8];
      f32x4 qa = *(const f32x4*)(qp + k * 8);
      f32x4 qb = *(const f32x4*)(qp + k * 8 + 4);
#pragma unroll
      for (int j = 0; j < 4; ++j) {
        float yv = qa[j] + bf2f(ov[j]) * linv;
        y[k * 8 + j] = yv;
        s1 += yv; s2 += yv * yv;
      }
#pragma unroll
      for (int j = 0; j < 4; ++j) {
        float yv = qb[j] + bf2f(ov[4 + j]) * linv;
        y[k * 8 + 4 + j] = yv;
        s1 += yv; s2 += yv * yv;
      }
    }
    s1 += __shfl_xor(s1, 1); s2 += __shfl_xor(s2, 1);
    s1 += __shfl_xor(s1, 2); s2 += __shfl_xor(s2, 2);
    s1 += __shfl_xor(s1, 4); s2 += __shfl_xor(s2, 4);
    float mean = s1 * (1.f / HID);
    float var = s2 * (1.f / HID) - mean * mean;
    float rstd = rsqrtf(var + 1e-5f);
#pragma unroll
    for (int k = 0; k < 4; ++k) {
      f32x4 wa = *(const f32x4*)(n0w + c0 + k * 8);
      f32x4 wb = *(const f32x4*)(n0w + c0 + k * 8 + 4);
      f32x4 ba = *(const f32x4*)(n0b + c0 + k * 8);
      f32x4 bb = *(const f32x4*)(n0b + c0 + k * 8 + 4);
      s16x4 o0, o1;
#pragma unroll
      for (int j = 0; j < 4; ++j) {
        o0[j] = f2bf((y[k * 8 + j] - mean) * rstd * wa[j] + ba[j]);
        o1[j] = f2bf((y[k * 8 + 4 + j] - mean) * rstd * wb[j] + bb[j]);
      }
      // in-place: this thread exclusively owns (row, c0..c0+31)
      *(s16x4*)&ob[row][c0 + k * 8] = o0;
      *(s16x4*)&ob[row][c0 + k * 8 + 4] = o1;
    }
  }
  BAR_LDS();  // x tile complete and visible

  // ---- FC GEMM + LN1 ----
  {
    f32x4 facc[8];
#pragma unroll
    for (int n2 = 0; n2 < 8; ++n2) facc[n2] = f32x4{0.f, 0.f, 0.f, 0.f};
#pragma unroll
    for (int ks = 0; ks < 8; ++ks) {
      bf16x8 a = *(const bf16x8*)&ob[qg * 16 + l16][ks * 32 + quad * 8];
#pragma unroll
      for (int n2 = 0; n2 < 8; ++n2) {
        int n = kh * 8 + n2;
        bf16x8 wb = *(const bf16x8*)(fwb + (size_t)((n * 8 + ks) * 64 + lane) * 8);
        facc[n2] = mfma16(a, wb, facc[n2]);
      }
    }
#pragma unroll
    for (int r = 0; r < 4; ++r) {
      int row = qg * 16 + quad * 4 + r;
      float s = 0.f, s2 = 0.f;
#pragma unroll
      for (int n2 = 0; n2 < 8; ++n2) {
        int col = kh * 128 + n2 * 16 + l16;
        float hres = fmaxf(facc[n2][r] + fcb[col], 0.f);
        float yv = bf2f(ob[row][col]) + hres;
        s += yv; s2 += yv * yv;
      }
      s += __shfl_xor(s, 1); s2 += __shfl_xor(s2, 1);
      s += __shfl_xor(s, 2); s2 += __shfl_xor(s2, 2);
      s += __shfl_xor(s, 4); s2 += __shfl_xor(s2, 4);
      s += __shfl_xor(s, 8); s2 += __shfl_xor(s2, 8);
      if (l16 == 0) { rs[0][kh][row] = s; rs[1][kh][row] = s2; }
    }
    BAR_LDS();
#pragma unroll
    for (int r = 0; r < 4; ++r) {
      int row = qg * 16 + quad * 4 + r;
      float st1 = rs[0][0][row] + rs[0][1][row];
      float st2 = rs[1][0][row] + rs[1][1][row];
      float mean = st1 * (1.f / HID);
      float var = st2 * (1.f / HID) - mean * mean;
      float rstd = rsqrtf(var + 1e-5f);
      float* op = out + (size_t)(qrow0 + row) * HID;
#pragma unroll
      for (int n2 = 0; n2 < 8; ++n2) {
        int col = kh * 128 + n2 * 16 + l16;
        float hres = fmaxf(facc[n2][r] + fcb[col], 0.f);
        float yv = bf2f(ob[row][col]) + hres;
        op[col] = (yv - mean) * rstd * n1w[col] + n1b[col];
      }
    }
  }
#undef LOADK
#undef VGLL
#undef GUARD_V
#undef S_PHASE
#undef PV_PHASE
#undef KT2_
}

extern "C" void kernel_launch(void* const* d_in, const int* in_sizes, int n_in,
                              void* d_out, int out_size, void* d_ws, size_t ws_size,
                              hipStream_t stream) {
  const float* q = (const float*)d_in[0];
  const float* h = (const float*)d_in[1];
  const float* WQ = (const float*)d_in[2];
  const float* WK = (const float*)d_in[3];
  const float* WV = (const float*)d_in[4];
  const float* fc_w = (const float*)d_in[5];
  const float* fc_b = (const float*)d_in[6];
  const float* n0w = (const float*)d_in[7];
  const float* n0b = (const float*)d_in[8];
  const float* n1w = (const float*)d_in[9];
  const float* n1b = (const float*)d_in[10];

  char* ws = (char*)d_ws;
  short* kb = (short*)(ws);                            //  4 MB  [0,4)  packed
  short* vt = (short*)(ws + ((size_t)4 << 20));        // 16 MB  [4,20) packed
  short* wqb = (short*)(ws + ((size_t)20 << 20));
  short* wkb = (short*)(ws + ((size_t)20 << 20) + 32 * 1024);
  short* wvb = (short*)(ws + ((size_t)20 << 20) + 64 * 1024);
  short* fwb = (short*)(ws + ((size_t)20 << 20) + 192 * 1024);

  cast4_kernel<<<640, 256, 0, stream>>>(WQ, wqb, QD * HID, WK, wkb, QD * HID,
                                        WV, wvb, HID * HID, fc_w, fwb, HID * HID);
  proj_kv_kernel<<<512, 256, 0, stream>>>(h, wkb, wvb, kb, vt);
  attn_kernel<<<512, 512, 0, stream>>>(q, wqb, kb, vt, fwb, fc_b,
                                       n0w, n0b, n1w, n1b, (float*)d_out);
}